// Round 1
// 275.243 us; speedup vs baseline: 1.0502x; 1.0502x over previous
//
#include <hip/hip_runtime.h>
#include <math.h>

// Problem constants (from setup_inputs): B=8, J=4, N=4, M=16, K=3, D=32768
constexpr int B_ = 8;
constexpr int J_ = 4;
constexpr int N_ = 4;
constexpr int M_ = 16;
constexpr int K_ = 3;
constexpr int D_ = 32768;
constexpr float EPS_ = 1e-8f;
constexpr float TEMP_INV = 2.0f;   // 1/TEMP, TEMP=0.5

constexpr int NEG_V = B_ * N_ * M_ * K_;    // 1536 neg vectors
constexpr int POS_V = B_ * K_;              // 24 pos vectors
constexpr int SEG   = 4;                    // D split into 4 segments
constexpr int SEG_F4 = D_ / 4 / SEG;        // 2048 float4 per segment
constexpr int NEG_BLOCKS = NEG_V * SEG;     // 6144
constexpr int POS_BLOCKS = POS_V * SEG;     // 96
constexpr int TOT_BLOCKS = NEG_BLOCKS + POS_BLOCKS;  // 6240

typedef float f4 __attribute__((ext_vector_type(4)));

#define FMA4(acc, p, q) \
  acc += (p).x * (q).x + (p).y * (q).y + (p).z * (q).z + (p).w * (q).w

// ---------------------------------------------------------------------------
// Kernel A: one block = one (vector, D-segment) partial. ATOMIC-FREE
// (R4/R5: same-address RMW chain ~45ns/block was the entire earlier
// regression). Partials go to UNIQUE ws slots via plain stores.
//
// This round:
//  - pos blocks FIRST (blockIdx < POS_BLOCKS) so the tiny pos tail is
//    absorbed inside the neg stream rather than trailing it.
//  - fmaps_neg loads are NONTEMPORAL: 201 MB zero-reuse stream was pushing
//    ~25 MB/XCD through the 4 MiB L2s each pass, evicting the 3 MB x slice
//    that every neg block re-reads (192 MB of re-reads). nt keeps x
//    L2-resident so the companion x loads stay low-latency.
// ---------------------------------------------------------------------------
__global__ __launch_bounds__(256) void partial_kernel(
    const float* __restrict__ fmaps, const float* __restrict__ fmaps_pos,
    const float* __restrict__ fmaps_neg,
    float* __restrict__ neg_dot_p, float* __restrict__ neg_nv_p,
    float* __restrict__ pos_dot_p, float* __restrict__ pos_nx_p,
    float* __restrict__ pos_np_p) {
  __shared__ float s[3][4];
  const int t = threadIdx.x;
  const int wid = t >> 6, lane = t & 63;

  if (blockIdx.x >= POS_BLOCKS) {
    // ---- neg partial: vid = ((b*N + n)*M + m)*K + k ----
    const int nid = blockIdx.x - POS_BLOCKS;
    const int vid = nid / SEG;
    const int seg = nid % SEG;
    const int k = vid % K_;
    const int b = vid / (N_ * M_ * K_);
    const size_t xbase = (((size_t)b * J_ + (J_ - 1)) * K_ + k) * (size_t)D_;
    const float4* __restrict__ xs =
        (const float4*)(fmaps + xbase) + (size_t)seg * SEG_F4;
    const f4* __restrict__ vs =
        (const f4*)(fmaps_neg + (size_t)vid * D_) + (size_t)seg * SEG_F4;

    float dot = 0.f, nv = 0.f;
#pragma unroll
    for (int u = 0; u < SEG_F4 / 256; ++u) {   // 8 fully-unrolled iters
      f4 c = __builtin_nontemporal_load(vs + t + 256 * u);  // HBM stream, nt
      float4 a = xs[t + 256 * u];                           // L2-resident x
      dot += a.x * c[0] + a.y * c[1] + a.z * c[2] + a.w * c[3];
      nv  += c[0] * c[0] + c[1] * c[1] + c[2] * c[2] + c[3] * c[3];
    }
    for (int off = 32; off > 0; off >>= 1) {
      dot += __shfl_down(dot, off, 64);
      nv  += __shfl_down(nv,  off, 64);
    }
    if (lane == 0) { s[0][wid] = dot; s[1][wid] = nv; }
    __syncthreads();
    if (t == 0) {
      neg_dot_p[nid] = s[0][0] + s[0][1] + s[0][2] + s[0][3];
      neg_nv_p[nid]  = s[1][0] + s[1][1] + s[1][2] + s[1][3];
    }
  } else {
    // ---- pos partial: vid = b*K + k ----
    const int pid = blockIdx.x;
    const int vid = pid / SEG;
    const int seg = pid % SEG;
    const int b = vid / K_, k = vid % K_;
    const size_t base = (((size_t)b * J_ + (J_ - 1)) * K_ + k) * (size_t)D_;
    const float4* __restrict__ xs =
        (const float4*)(fmaps + base) + (size_t)seg * SEG_F4;
    const float4* __restrict__ ps =
        (const float4*)(fmaps_pos + base) + (size_t)seg * SEG_F4;

    float dot = 0.f, nx = 0.f, np = 0.f;
#pragma unroll
    for (int u = 0; u < SEG_F4 / 256; ++u) {
      float4 a = xs[t + 256 * u];
      float4 c = ps[t + 256 * u];
      FMA4(dot, a, c);
      FMA4(nx, a, a);
      FMA4(np, c, c);
    }
    for (int off = 32; off > 0; off >>= 1) {
      dot += __shfl_down(dot, off, 64);
      nx  += __shfl_down(nx,  off, 64);
      np  += __shfl_down(np,  off, 64);
    }
    if (lane == 0) { s[0][wid] = dot; s[1][wid] = nx; s[2][wid] = np; }
    __syncthreads();
    if (t == 0) {
      pos_dot_p[pid] = s[0][0] + s[0][1] + s[0][2] + s[0][3];
      pos_nx_p[pid]  = s[1][0] + s[1][1] + s[1][2] + s[1][3];
      pos_np_p[pid]  = s[2][0] + s[2][1] + s[2][2] + s[2][3];
    }
  }
}

// ---------------------------------------------------------------------------
// Kernel B: single block, 1024 threads. Partials were written by 6240 blocks
// spread over 8 XCDs, so reads here mostly miss the local L2 -> L3
// (~300-500 cyc). Maximize MLP: float4 loads (SEG=4 partials are contiguous
// and 16B aligned), all loads independent, 4x the threads of the old
// version -> one latency round instead of several.
// ---------------------------------------------------------------------------
__global__ __launch_bounds__(1024) void finish_kernel(
    const float* __restrict__ neg_dot_p, const float* __restrict__ neg_nv_p,
    const float* __restrict__ pos_dot_p, const float* __restrict__ pos_nx_p,
    const float* __restrict__ pos_np_p,
    const int* __restrict__ gt_labels, const int* __restrict__ gt_label_negs,
    float* __restrict__ out) {
  __shared__ float l_neg[NEG_V];
  __shared__ float l_pos[POS_V];
  __shared__ float l_nxs[POS_V];
  __shared__ float red[4];
  const int t = threadIdx.x;

  // pos logits + |x| per (b,k)
  if (t < POS_V) {
    const float4 d4 = *(const float4*)(pos_dot_p + t * SEG);
    const float4 x4 = *(const float4*)(pos_nx_p + t * SEG);
    const float4 p4 = *(const float4*)(pos_np_p + t * SEG);
    const float dot = d4.x + d4.y + d4.z + d4.w;
    const float nx  = x4.x + x4.y + x4.z + x4.w;
    const float np  = p4.x + p4.y + p4.z + p4.w;
    const float nxs = sqrtf(nx);
    l_nxs[t] = nxs;
    l_pos[t] = dot / fmaxf(nxs * sqrtf(np), EPS_) * TEMP_INV;
  }
  __syncthreads();

  // neg logits: 1024 threads, <=2 vids each, independent float4 loads
  for (int vid = t; vid < NEG_V; vid += 1024) {
    const float4 d4 = *(const float4*)(neg_dot_p + vid * SEG);
    const float4 n4 = *(const float4*)(neg_nv_p + vid * SEG);
    const float dot = d4.x + d4.y + d4.z + d4.w;
    const float nv  = n4.x + n4.y + n4.z + n4.w;
    const int k = vid % K_;
    const int b = vid / (N_ * M_ * K_);
    l_neg[vid] =
        dot / fmaxf(l_nxs[b * K_ + k] * sqrtf(nv), EPS_) * TEMP_INV;
  }
  __syncthreads();

  // masked logsumexp: 8 threads per (b,k), first 256 threads only.
  // Logits bounded in [-2,2] (cosine/TEMP) so no max-shift needed.
  if (t < 256) {
    const int bk = t >> 3, sub = t & 7;
    float partial = 0.f;
    if (bk < POS_V) {
      const int b = bk / K_, k = bk % K_;
      const int lbl = gt_labels[b * J_ + (J_ - 1)];
      for (int u = 0; u < 8; ++u) {
        const int i = sub * 8 + u;                  // n*M+m in 0..63
        if (gt_label_negs[b * (N_ * M_) + i] == lbl) {
          partial += expf(l_neg[(b * (N_ * M_) + i) * K_ + k]);
        }
      }
    }
    for (int off = 1; off < 8; off <<= 1)
      partial += __shfl_xor(partial, off, 64);

    float contrib = 0.f;
    if (bk < POS_V && sub == 0) {
      const float p = l_pos[bk];
      contrib = logf(partial + expf(p)) - p;
    }
    for (int off = 32; off > 0; off >>= 1)
      contrib += __shfl_down(contrib, off, 64);
    if ((t & 63) == 0) red[t >> 6] = contrib;
  }
  __syncthreads();
  if (t == 0) out[0] = (red[0] + red[1] + red[2] + red[3]) / (2.0f * (float)B_);
}

// ---------------------------------------------------------------------------
extern "C" void kernel_launch(void* const* d_in, const int* in_sizes, int n_in,
                              void* d_out, int out_size, void* d_ws, size_t ws_size,
                              hipStream_t stream) {
  const float* fmaps         = (const float*)d_in[0];
  const float* fmaps_pos     = (const float*)d_in[1];
  const float* fmaps_neg     = (const float*)d_in[2];
  const int*   gt_labels     = (const int*)d_in[3];
  const int*   gt_label_negs = (const int*)d_in[4];
  float* out = (float*)d_out;

  // ws layout (floats), all plain stores, no init needed:
  // [0,6144)      neg_dot_p
  // [6144,12288)  neg_nv_p
  // [12288,12384) pos_dot_p
  // [12384,12480) pos_nx_p
  // [12480,12576) pos_np_p
  float* ws        = (float*)d_ws;
  float* neg_dot_p = ws;
  float* neg_nv_p  = ws + NEG_BLOCKS;
  float* pos_dot_p = ws + 2 * NEG_BLOCKS;
  float* pos_nx_p  = ws + 2 * NEG_BLOCKS + POS_BLOCKS;
  float* pos_np_p  = ws + 2 * NEG_BLOCKS + 2 * POS_BLOCKS;

  partial_kernel<<<TOT_BLOCKS, 256, 0, stream>>>(
      fmaps, fmaps_pos, fmaps_neg,
      neg_dot_p, neg_nv_p, pos_dot_p, pos_nx_p, pos_np_p);
  finish_kernel<<<1, 1024, 0, stream>>>(
      neg_dot_p, neg_nv_p, pos_dot_p, pos_nx_p, pos_np_p,
      gt_labels, gt_label_negs, out);
}